// Round 2
// baseline (136.191 us; speedup 1.0000x reference)
//
#include <hip/hip_runtime.h>

#define DIMH 9
#define SRF 24000.0f

typedef float f4 __attribute__((ext_vector_type(4)));
typedef float f2 __attribute__((ext_vector_type(2)));

// Phase 1: per-(b,k) running sum of per-frame phase increments (double acc),
// store only frac(upp * prefix) as float — the integer part is mod-1 invisible.
__global__ void scan_kernel(const float* __restrict__ f0,
                            const float* __restrict__ rand_ini,
                            float* __restrict__ Pf, int T, int upp) {
    extern __shared__ float sf0[];
    int b = blockIdx.x;
    for (int i = threadIdx.x; i < T; i += blockDim.x)
        sf0[i] = f0[(size_t)b * T + i];
    __syncthreads();
    int k = threadIdx.x;
    if (k < DIMH) {
        double acc = 0.0;
        float hk = (float)(k + 1);
        float* Pr = Pf + ((size_t)b * DIMH + k) * T;
        double du = (double)upp;
        for (int t = 0; t < T; ++t) {
            float x = sf0[t] * hk / SRF;      // matches f0*(k+1)/SR in f32
            float rad = x - truncf(x);         // frac, x >= 0
            if (t == 0) rad += rand_ini[b * DIMH + k];
            acc += (double)rad;
            double up = acc * du;              // upp=256: exact scaling
            Pr[t] = (float)(up - (double)(long long)up);  // frac(upp*P) in [0,1)
        }
    }
}

// Phase 2: one block per (b, frame t). Pure-f32 hot loop, float4 streams.
__global__ __launch_bounds__(256) void sine_kernel(
    const float* __restrict__ f0, const float* __restrict__ rand_ini,
    const float* __restrict__ noise_z, const float* __restrict__ Pf,
    float* __restrict__ out, int B, int T, int upp)
{
    int gb = blockIdx.x;          // b*T + t
    int b = gb / T;
    int t = gb - b * T;
    int tid = threadIdx.x;

    __shared__ f2 srp[DIMH];      // {rad[t,k], frac(upp*P[t-1,k])}

    float f0v = f0[(size_t)b * T + t];
    if (tid < DIMH) {
        float x = f0v * (float)(tid + 1) / SRF;
        float rad = x - truncf(x);
        if (t == 0) rad += rand_ini[b * DIMH + tid];
        f2 v;
        v.x = rad;
        v.y = (t > 0) ? Pf[((size_t)b * DIMH + tid) * T + (t - 1)] : 0.0f;
        srp[tid] = v;
    }
    __syncthreads();

    float uv   = (f0v > 0.0f) ? 1.0f : 0.0f;
    float namp = uv * 0.003f + (1.0f - uv) * (0.1f / 3.0f);

    size_t L = (size_t)T * (size_t)upp;
    float* out_sine  = out;
    float* out_uv    = out + (size_t)B * L * DIMH;
    float* out_noise = out_uv + (size_t)B * L;

    // uv stream: upp floats -> upp/4 float4
    {
        f4 uvv = {uv, uv, uv, uv};
        f4* uvp = (f4*)(out_uv + (size_t)b * L + (size_t)t * upp);
        int nuv = upp >> 2;
        for (int i = tid; i < nuv; i += 256)
            __builtin_nontemporal_store(uvv, uvp + i);
    }

    size_t frame_base = ((size_t)b * L + (size_t)t * upp) * DIMH;
    const f4* nzp = (const f4*)(noise_z + frame_base);
    f4* sp = (f4*)(out_sine + frame_base);
    f4* np = (f4*)(out_noise + frame_base);

    int nv = (upp * DIMH) >> 2;   // 576 float4 per frame
    for (int v = tid; v < nv; v += 256) {
        int e0 = v << 2;
        int rr = e0 / DIMH;        // magic-mul (constexpr divisor)
        int k  = e0 - rr * DIMH;
        f4 nz = __builtin_nontemporal_load(nzp + v);
        f4 sv, nov;
        #pragma unroll
        for (int j = 0; j < 4; ++j) {
            f2 rp = srp[k];
            float C  = fmaf((float)(rr + 1), rp.x, rp.y);   // |C| <= 257
            float fr = C - truncf(C);                       // frac, C >= 0
#if __has_builtin(__builtin_amdgcn_sinf)
            float s = __builtin_amdgcn_sinf(fr) * 0.1f;     // v_sin_f32: revolutions
#else
            float s = sinf(6.283185307179586f * fr) * 0.1f;
#endif
            float no = namp * nz[j];
            sv[j]  = fmaf(s, uv, no);
            nov[j] = no;
            if (++k == DIMH) { k = 0; ++rr; }
        }
        __builtin_nontemporal_store(sv, sp + v);
        __builtin_nontemporal_store(nov, np + v);
    }
}

extern "C" void kernel_launch(void* const* d_in, const int* in_sizes, int n_in,
                              void* d_out, int out_size, void* d_ws, size_t ws_size,
                              hipStream_t stream) {
    const float* f0       = (const float*)d_in[0];
    const float* rand_ini = (const float*)d_in[1];
    const float* noise_z  = (const float*)d_in[2];
    float* out = (float*)d_out;

    int B = in_sizes[1] / DIMH;                        // 16
    int T = in_sizes[0] / B;                           // 800
    long long L = (long long)(in_sizes[2] / DIMH) / B; // 204800
    int upp = (int)(L / T);                            // 256

    float* Pf = (float*)d_ws;                          // B*9*T floats (~0.46 MB)

    scan_kernel<<<B, 256, T * (int)sizeof(float), stream>>>(f0, rand_ini, Pf, T, upp);
    sine_kernel<<<B * T, 256, 0, stream>>>(f0, rand_ini, noise_z, Pf, out, B, T, upp);
}

// Round 3
// 82.807 us; speedup vs baseline: 1.6447x; 1.6447x over previous
//
#include <hip/hip_runtime.h>

#define DIMH 9
#define FRAMES 4

typedef float f4 __attribute__((ext_vector_type(4)));
typedef float f2 __attribute__((ext_vector_type(2)));

// Phase 1: parallel prefix-sum of per-frame phase increments.
// One block per (b,k); 256 threads x 4 frames each; f64 accumulation.
// Pf[(b*9+k)*T + t] = frac(upp * sum_{s<=t} rad[b,s,k])  (rand_ini folded at s=0)
__global__ __launch_bounds__(256) void scan_kernel(
    const float* __restrict__ f0, const float* __restrict__ rand_ini,
    float* __restrict__ Pf, int B, int T, int upp)
{
    int bk = blockIdx.x;            // b*DIMH + k
    int b = bk / DIMH;
    int k = bk - b * DIMH;
    int tid = threadIdx.x;
    float hk = (float)(k + 1);

    int t0 = tid * 4;               // T == 800, multiple of 4
    f4 fv = {0.f, 0.f, 0.f, 0.f};
    if (t0 < T) fv = *(const f4*)(f0 + (size_t)b * T + t0);

    double s[4];
    double run = 0.0;
    #pragma unroll
    for (int j = 0; j < 4; ++j) {
        float x = fv[j] * hk * (1.0f / 24000.0f);
        float rad = x - truncf(x);                 // frac, x >= 0
        if (t0 == 0 && j == 0) rad += rand_ini[b * DIMH + k];
        run += (double)rad;
        s[j] = run;
    }

    // inclusive wave scan of per-thread totals
    double tot = run;
    int lane = tid & 63;
    #pragma unroll
    for (int d = 1; d < 64; d <<= 1) {
        double u = __shfl_up(tot, d);
        if (lane >= d) tot += u;
    }
    __shared__ double wsum[4];
    int wid = tid >> 6;
    if (lane == 63) wsum[wid] = tot;
    __syncthreads();
    double excl = tot - run;                       // exclusive within wave
    for (int w = 0; w < wid; ++w) excl += wsum[w]; // wave-uniform loop

    if (t0 < T) {
        f4 o;
        double du = (double)upp;
        #pragma unroll
        for (int j = 0; j < 4; ++j) {
            double up = (excl + s[j]) * du;
            o[j] = (float)(up - (double)(long long)up);   // frac in [0,1)
        }
        *(f4*)(Pf + ((size_t)bk) * (size_t)T + t0) = o;
    }
}

// Phase 2: one block per (b, 4 frames). Pure-f32 hot loop, float4 streams.
__global__ __launch_bounds__(256) void sine_kernel(
    const float* __restrict__ f0, const float* __restrict__ rand_ini,
    const float* __restrict__ noise_z, const float* __restrict__ Pf,
    float* __restrict__ out, int B, int T, int upp)
{
    int nfb = T / FRAMES;           // frame-groups per batch (200)
    int gb = blockIdx.x;
    int b = gb / nfb;
    int t0 = (gb - b * nfb) * FRAMES;
    int tid = threadIdx.x;

    __shared__ f2 srp[FRAMES * DIMH];   // {rad[t,k], frac(upp*P[t-1,k])}
    __shared__ float suv[FRAMES], snamp[FRAMES];

    if (tid < FRAMES * DIMH) {
        int tl = tid / DIMH;            // const-9 divisor -> magic mul
        int k  = tid - tl * DIMH;
        int t  = t0 + tl;
        float f0v = f0[(size_t)b * T + t];
        float x = f0v * (float)(k + 1) * (1.0f / 24000.0f);
        float rad = x - truncf(x);
        if (t == 0) rad += rand_ini[b * DIMH + k];
        f2 v;
        v.x = rad;
        v.y = (t > 0) ? Pf[((size_t)b * DIMH + k) * T + (t - 1)] : 0.0f;
        srp[tid] = v;
        if (k == 0) {
            float uv = (f0v > 0.0f) ? 1.0f : 0.0f;
            suv[tl] = uv;
            snamp[tl] = uv * 0.003f + (1.0f - uv) * (0.1f / 3.0f);
        }
    }
    __syncthreads();

    size_t L = (size_t)T * (size_t)upp;
    float* out_sine  = out;
    float* out_uv    = out + (size_t)B * L * DIMH;
    float* out_noise = out_uv + (size_t)B * L;

    // uv: FRAMES*upp floats = 256 f4 -> one per thread
    {
        int f = tid >> 6;               // 64 f4 per frame (upp=256)
        float u = suv[f];
        f4 uvv = {u, u, u, u};
        f4* uvp = (f4*)(out_uv + (size_t)b * L + (size_t)t0 * upp);
        __builtin_nontemporal_store(uvv, uvp + tid);
    }

    size_t base = ((size_t)b * L + (size_t)t0 * upp) * DIMH;
    const f4* nzp = (const f4*)(noise_z + base);
    f4* sp = (f4*)(out_sine + base);
    f4* np = (f4*)(out_noise + base);

    int fpf   = upp * DIMH / 4;         // f4 per frame (576)
    int totf4 = FRAMES * fpf;           // 2304 -> 9 iters/thread
    int vf = tid, fidx = 0;             // incremental (frame, within-frame) tracking
    for (int v = tid; v < totf4; v += 256) {
        int e0 = vf << 2;
        int rr = e0 / DIMH;             // const-9 divisor
        int k  = e0 - rr * DIMH;
        float uv   = suv[fidx];
        float namp = snamp[fidx];
        f4 nz = __builtin_nontemporal_load(nzp + v);
        f4 sv, nov;
        #pragma unroll
        for (int j = 0; j < 4; ++j) {
            f2 rp = srp[fidx * DIMH + k];
            float C  = fmaf((float)(rr + 1), rp.x, rp.y);   // |C| <= 257
            float fr = C - truncf(C);                       // frac, C >= 0
#if __has_builtin(__builtin_amdgcn_sinf)
            float s = __builtin_amdgcn_sinf(fr) * 0.1f;     // v_sin_f32: revolutions in
#else
            float s = sinf(6.283185307179586f * fr) * 0.1f;
#endif
            float no = namp * nz[j];
            sv[j]  = fmaf(s, uv, no);
            nov[j] = no;
            if (++k == DIMH) { k = 0; ++rr; }
        }
        __builtin_nontemporal_store(sv, sp + v);
        __builtin_nontemporal_store(nov, np + v);
        vf += 256;
        if (vf >= fpf) { vf -= fpf; ++fidx; }
    }
}

extern "C" void kernel_launch(void* const* d_in, const int* in_sizes, int n_in,
                              void* d_out, int out_size, void* d_ws, size_t ws_size,
                              hipStream_t stream) {
    const float* f0       = (const float*)d_in[0];
    const float* rand_ini = (const float*)d_in[1];
    const float* noise_z  = (const float*)d_in[2];
    float* out = (float*)d_out;

    int B = in_sizes[1] / DIMH;                        // 16
    int T = in_sizes[0] / B;                           // 800
    long long L = (long long)(in_sizes[2] / DIMH) / B; // 204800
    int upp = (int)(L / T);                            // 256

    float* Pf = (float*)d_ws;                          // B*9*T floats (~0.46 MB)

    scan_kernel<<<B * DIMH, 256, 0, stream>>>(f0, rand_ini, Pf, B, T, upp);
    sine_kernel<<<B * (T / FRAMES), 256, 0, stream>>>(f0, rand_ini, noise_z, Pf,
                                                      out, B, T, upp);
}

// Round 4
// 80.074 us; speedup vs baseline: 1.7008x; 1.0341x over previous
//
#include <hip/hip_runtime.h>

#define DIMH 9
#define FRAMES 4

typedef float f4 __attribute__((ext_vector_type(4)));
typedef float f2 __attribute__((ext_vector_type(2)));

// Phase 1: parallel prefix-sum of per-frame phase increments.
// One block per (b,k); 256 threads x 4 frames each; f64 accumulation.
// Pf[(b*9+k)*T + t] = frac(upp * sum_{s<=t} rad[b,s,k])  (rand_ini folded at s=0)
__global__ __launch_bounds__(256) void scan_kernel(
    const float* __restrict__ f0, const float* __restrict__ rand_ini,
    float* __restrict__ Pf, int B, int T, int upp)
{
    int bk = blockIdx.x;            // b*DIMH + k
    int b = bk / DIMH;
    int k = bk - b * DIMH;
    int tid = threadIdx.x;
    float hk = (float)(k + 1);

    int t0 = tid * 4;               // T == 800, multiple of 4
    f4 fv = {0.f, 0.f, 0.f, 0.f};
    if (t0 < T) fv = *(const f4*)(f0 + (size_t)b * T + t0);

    double s[4];
    double run = 0.0;
    #pragma unroll
    for (int j = 0; j < 4; ++j) {
        float x = fv[j] * hk * (1.0f / 24000.0f);
        float rad = x - truncf(x);                 // frac, x >= 0
        if (t0 == 0 && j == 0) rad += rand_ini[b * DIMH + k];
        run += (double)rad;
        s[j] = run;
    }

    // inclusive wave scan of per-thread totals
    double tot = run;
    int lane = tid & 63;
    #pragma unroll
    for (int d = 1; d < 64; d <<= 1) {
        double u = __shfl_up(tot, d);
        if (lane >= d) tot += u;
    }
    __shared__ double wsum[4];
    int wid = tid >> 6;
    if (lane == 63) wsum[wid] = tot;
    __syncthreads();
    double excl = tot - run;                       // exclusive within wave
    for (int w = 0; w < wid; ++w) excl += wsum[w]; // wave-uniform loop

    if (t0 < T) {
        f4 o;
        double du = (double)upp;
        #pragma unroll
        for (int j = 0; j < 4; ++j) {
            double up = (excl + s[j]) * du;
            o[j] = (float)(up - (double)(long long)up);   // frac in [0,1)
        }
        *(f4*)(Pf + ((size_t)bk) * (size_t)T + t0) = o;
    }
}

// Shared body: per-block setup of {rad, fracP, uv, namp} for FRAMES frames.
__device__ __forceinline__ void setup_frames(
    const float* __restrict__ f0, const float* __restrict__ rand_ini,
    const float* __restrict__ Pf, int b, int t0, int T, int tid,
    f2* srp, float* suv, float* snamp)
{
    if (tid < FRAMES * DIMH) {
        int tl = tid / DIMH;            // const-9 divisor -> magic mul
        int k  = tid - tl * DIMH;
        int t  = t0 + tl;
        float f0v = f0[(size_t)b * T + t];
        float x = f0v * (float)(k + 1) * (1.0f / 24000.0f);
        float rad = x - truncf(x);
        if (t == 0) rad += rand_ini[b * DIMH + k];
        f2 v;
        v.x = rad;
        v.y = (t > 0) ? Pf[((size_t)b * DIMH + k) * T + (t - 1)] : 0.0f;
        srp[tid] = v;
        if (k == 0) {
            float uv = (f0v > 0.0f) ? 1.0f : 0.0f;
            suv[tl] = uv;
            snamp[tl] = uv * 0.003f + (1.0f - uv) * (0.1f / 3.0f);
        }
    }
}

// Phase 2 (UPP compile-time): one block per (b, 4 frames). Fully-unrolled,
// no loop-carried state -> all 9 nz loads pipeline ahead of sin/store chain.
template <int UPP>
__global__ __launch_bounds__(256) void sine_kernel_t(
    const float* __restrict__ f0, const float* __restrict__ rand_ini,
    const float* __restrict__ noise_z, const float* __restrict__ Pf,
    float* __restrict__ out, int B, int T)
{
    int nfb = T / FRAMES;
    int gb = blockIdx.x;
    int b = gb / nfb;
    int t0 = (gb - b * nfb) * FRAMES;
    int tid = threadIdx.x;

    __shared__ f2 srp[FRAMES * DIMH];
    __shared__ float suv[FRAMES], snamp[FRAMES];
    setup_frames(f0, rand_ini, Pf, b, t0, T, tid, srp, suv, snamp);
    __syncthreads();

    size_t L = (size_t)T * (size_t)UPP;
    float* out_sine  = out;
    float* out_uv    = out + (size_t)B * L * DIMH;
    float* out_noise = out_uv + (size_t)B * L;

    // uv: FRAMES*UPP floats = 256 f4 -> one per thread
    {
        int f = tid >> 6;               // 64 f4 per frame (UPP=256)
        float u = suv[f];
        f4 uvv = {u, u, u, u};
        f4* uvp = (f4*)(out_uv + (size_t)b * L + (size_t)t0 * UPP);
        __builtin_nontemporal_store(uvv, uvp + tid);
    }

    size_t base = ((size_t)b * L + (size_t)t0 * UPP) * DIMH;
    const f4* nzp = (const f4*)(noise_z + base);
    f4* sp = (f4*)(out_sine + base);
    f4* np = (f4*)(out_noise + base);

    constexpr int NIT = FRAMES * UPP * DIMH / 4 / 256;   // 9 when UPP=256
    #pragma unroll
    for (int it = 0; it < NIT; ++it) {
        int v  = tid + it * 256;
        int e0 = v << 2;
        int s  = e0 / DIMH;             // const-9 magic mul, no carried dep
        int k  = e0 - s * DIMH;
        int fidx = s / UPP;             // shift (UPP pow2)
        int rr   = s - fidx * UPP;
        float uv   = suv[fidx];
        float namp = snamp[fidx];
        f4 nz = __builtin_nontemporal_load(nzp + v);
        f4 sv, nov;
        #pragma unroll
        for (int j = 0; j < 4; ++j) {
            f2 rp = srp[fidx * DIMH + k];
            float C  = fmaf((float)(rr + 1), rp.x, rp.y);   // |C| <= UPP+1
            float fr = C - truncf(C);                       // frac, C >= 0
#if __has_builtin(__builtin_amdgcn_sinf)
            float sn = __builtin_amdgcn_sinf(fr) * 0.1f;    // v_sin_f32: revolutions
#else
            float sn = sinf(6.283185307179586f * fr) * 0.1f;
#endif
            float no = namp * nz[j];
            sv[j]  = fmaf(sn, uv, no);
            nov[j] = no;
            if (++k == DIMH) { k = 0; ++rr; }               // within-f4 only
        }
        __builtin_nontemporal_store(sv, sp + v);
        __builtin_nontemporal_store(nov, np + v);
    }
}

// Runtime-upp fallback (unused in this bench; kept for safety).
__global__ __launch_bounds__(256) void sine_kernel_rt(
    const float* __restrict__ f0, const float* __restrict__ rand_ini,
    const float* __restrict__ noise_z, const float* __restrict__ Pf,
    float* __restrict__ out, int B, int T, int upp)
{
    int nfb = T / FRAMES;
    int gb = blockIdx.x;
    int b = gb / nfb;
    int t0 = (gb - b * nfb) * FRAMES;
    int tid = threadIdx.x;

    __shared__ f2 srp[FRAMES * DIMH];
    __shared__ float suv[FRAMES], snamp[FRAMES];
    setup_frames(f0, rand_ini, Pf, b, t0, T, tid, srp, suv, snamp);
    __syncthreads();

    size_t L = (size_t)T * (size_t)upp;
    float* out_sine  = out;
    float* out_uv    = out + (size_t)B * L * DIMH;
    float* out_noise = out_uv + (size_t)B * L;

    for (int i = tid; i < FRAMES * upp / 4; i += 256) {
        int f = i / (upp >> 2);
        float u = suv[f];
        f4 uvv = {u, u, u, u};
        ((f4*)(out_uv + (size_t)b * L + (size_t)t0 * upp))[i] = uvv;
    }

    size_t base = ((size_t)b * L + (size_t)t0 * upp) * DIMH;
    const f4* nzp = (const f4*)(noise_z + base);
    f4* sp = (f4*)(out_sine + base);
    f4* np = (f4*)(out_noise + base);

    int totf4 = FRAMES * upp * DIMH / 4;
    for (int v = tid; v < totf4; v += 256) {
        int e0 = v << 2;
        int s  = e0 / DIMH;
        int k  = e0 - s * DIMH;
        int fidx = s / upp;
        int rr   = s - fidx * upp;
        float uv   = suv[fidx];
        float namp = snamp[fidx];
        f4 nz = nzp[v];
        f4 sv, nov;
        #pragma unroll
        for (int j = 0; j < 4; ++j) {
            f2 rp = srp[fidx * DIMH + k];
            float C  = fmaf((float)(rr + 1), rp.x, rp.y);
            float fr = C - truncf(C);
            float sn = sinf(6.283185307179586f * fr) * 0.1f;
            float no = namp * nz[j];
            sv[j]  = fmaf(sn, uv, no);
            nov[j] = no;
            if (++k == DIMH) { k = 0; ++rr; }
        }
        sp[v] = sv;
        np[v] = nov;
    }
}

extern "C" void kernel_launch(void* const* d_in, const int* in_sizes, int n_in,
                              void* d_out, int out_size, void* d_ws, size_t ws_size,
                              hipStream_t stream) {
    const float* f0       = (const float*)d_in[0];
    const float* rand_ini = (const float*)d_in[1];
    const float* noise_z  = (const float*)d_in[2];
    float* out = (float*)d_out;

    int B = in_sizes[1] / DIMH;                        // 16
    int T = in_sizes[0] / B;                           // 800
    long long L = (long long)(in_sizes[2] / DIMH) / B; // 204800
    int upp = (int)(L / T);                            // 256

    float* Pf = (float*)d_ws;                          // B*9*T floats (~0.46 MB)

    scan_kernel<<<B * DIMH, 256, 0, stream>>>(f0, rand_ini, Pf, B, T, upp);
    if (upp == 256) {
        sine_kernel_t<256><<<B * (T / FRAMES), 256, 0, stream>>>(
            f0, rand_ini, noise_z, Pf, out, B, T);
    } else {
        sine_kernel_rt<<<B * (T / FRAMES), 256, 0, stream>>>(
            f0, rand_ini, noise_z, Pf, out, B, T, upp);
    }
}